// Round 7
// baseline (626.033 us; speedup 1.0000x reference)
//
#include <hip/hip_runtime.h>
#include <math.h>

#define NN 50000
#define NE 800000
#define TW 10

static __device__ __forceinline__ float sigf(float x){ return 1.0f/(1.0f+__expf(-x)); }
static __device__ __forceinline__ float tanhfast(float x){
  float e2 = __expf(2.0f*x);
  return 1.0f - 2.0f/(e2 + 1.0f);
}
// bf16 pack/unpack (RNE)
static __device__ __forceinline__ unsigned f2bf(float f){
  unsigned u = __float_as_uint(f);
  return (u + 0x7FFFu + ((u>>16)&1u)) >> 16;
}
static __device__ __forceinline__ unsigned pack2(float a, float b){
  return f2bf(a) | (f2bf(b) << 16);
}
static __device__ __forceinline__ float bflo(unsigned u){ return __uint_as_float(u << 16); }
static __device__ __forceinline__ float bfhi(unsigned u){ return __uint_as_float(u & 0xFFFF0000u); }

// ---------------- degree ----------------
__global__ void k_degree(const int* __restrict__ src, const int* __restrict__ dst,
                         int* __restrict__ dego, int* __restrict__ degi){
  int e = blockIdx.x*256 + threadIdx.x;
  if (e < NE){
    atomicAdd(&dego[src[e]], 1);
    atomicAdd(&degi[dst[e]], 1);
  }
}

// ---------------- scan block-sum + norms (fused) ----------------
__global__ void k_scan1n(const int* __restrict__ degi, const int* __restrict__ dego,
                         int* __restrict__ bsum, float* __restrict__ ns,
                         float* __restrict__ nd, unsigned* __restrict__ maxbuf){
  __shared__ int s[512];
  int i = blockIdx.x*512 + threadIdx.x;
  int v = (i < NN) ? degi[i] : 0;
  s[threadIdx.x] = v;
  if (i < NN){
    int a = dego[i]; if (a < 1) a = 1;
    int b = v;       if (b < 1) b = 1;
    ns[i] = rsqrtf((float)a);
    nd[i] = rsqrtf((float)b);
  }
  if (blockIdx.x == 0 && threadIdx.x < 8) maxbuf[threadIdx.x] = 0x3FFFFFFFu; // map(-2.0f)
  __syncthreads();
  for (int st = 256; st > 0; st >>= 1){
    if (threadIdx.x < st) s[threadIdx.x] += s[threadIdx.x + st];
    __syncthreads();
  }
  if (threadIdx.x == 0) bsum[blockIdx.x] = s[0];
}

__global__ void k_scan2(int* __restrict__ bsum, int nb, int* __restrict__ row_start){
  if (blockIdx.x == 0 && threadIdx.x == 0){
    int run = 0;
    for (int b = 0; b < nb; ++b){ int v = bsum[b]; bsum[b] = run; run += v; }
    row_start[NN] = run;
  }
}

__global__ void k_scan3(const int* __restrict__ degi, const int* __restrict__ boff,
                        int* __restrict__ row_start){
  __shared__ int s[512];
  int i = blockIdx.x*512 + threadIdx.x;
  int v = (i < NN) ? degi[i] : 0;
  s[threadIdx.x] = v;
  __syncthreads();
  for (int st = 1; st < 512; st <<= 1){
    int add = (threadIdx.x >= st) ? s[threadIdx.x - st] : 0;
    __syncthreads();
    s[threadIdx.x] += add;
    __syncthreads();
  }
  if (i < NN) row_start[i] = boff[blockIdx.x] + s[threadIdx.x] - v; // exclusive
}

__global__ void k_fill(const int* __restrict__ src, const int* __restrict__ dst,
                       const int* __restrict__ row_start, int* __restrict__ cursor,
                       int* __restrict__ csr){
  int e = blockIdx.x*256 + threadIdx.x;
  if (e < NE){
    int d = dst[e];
    int p = atomicAdd(&cursor[d], 1);
    csr[row_start[d] + p] = src[e];
  }
}

// ---------------- conv1: h1[n][t] = bf16( (feat[t][n]) @ W1 * ns[n] ) ----------------
// 16 lanes cooperate per row (unchanged from R6 — measured good).
#define CONV1_BLOCKS 2000
__global__ __launch_bounds__(256) void k_conv1(const float* __restrict__ feat,
                                               const float* __restrict__ W1,
                                               const float* __restrict__ ns,
                                               uint4* __restrict__ h1){
  __shared__ float4 w[256];
  int tid = threadIdx.x;
  w[tid] = ((const float4*)W1)[tid];
  __syncthreads();
  int lane = tid & 15;
  float4 wa[8], wb[8];
  #pragma unroll
  for (int d = 0; d < 8; ++d){
    wa[d] = w[(lane*8 + d)*2 + 0];
    wb[d] = w[(lane*8 + d)*2 + 1];
  }
  int gid = (blockIdx.x*256 + tid) >> 4;
  const int ngroups = CONV1_BLOCKS*16;
  for (int r = gid; r < TW*NN; r += ngroups){
    const float4* frow = (const float4*)feat + (long long)r*32 + lane*2;
    float4 f0 = frow[0], f1 = frow[1];
    float fs[8] = {f0.x,f0.y,f0.z,f0.w,f1.x,f1.y,f1.z,f1.w};
    float acc[8] = {0,0,0,0,0,0,0,0};
    #pragma unroll
    for (int d = 0; d < 8; ++d){
      float fv = fs[d];
      acc[0] += fv*wa[d].x; acc[1] += fv*wa[d].y; acc[2] += fv*wa[d].z; acc[3] += fv*wa[d].w;
      acc[4] += fv*wb[d].x; acc[5] += fv*wb[d].y; acc[6] += fv*wb[d].z; acc[7] += fv*wb[d].w;
    }
    int b8 = (lane>>3)&1, b4 = (lane>>2)&1, b2 = (lane>>1)&1;
    float s0 = b8 ? acc[0] : acc[4], s1 = b8 ? acc[1] : acc[5];
    float s2 = b8 ? acc[2] : acc[6], s3 = b8 ? acc[3] : acc[7];
    float k0 = b8 ? acc[4] : acc[0], k1 = b8 ? acc[5] : acc[1];
    float k2 = b8 ? acc[6] : acc[2], k3 = b8 ? acc[7] : acc[3];
    k0 += __shfl_xor(s0, 8); k1 += __shfl_xor(s1, 8);
    k2 += __shfl_xor(s2, 8); k3 += __shfl_xor(s3, 8);
    float t0 = b4 ? k0 : k2, t1 = b4 ? k1 : k3;
    float m0 = b4 ? k2 : k0, m1 = b4 ? k3 : k1;
    m0 += __shfl_xor(t0, 4); m1 += __shfl_xor(t1, 4);
    float u1 = b2 ? m0 : m1;
    float v0 = b2 ? m1 : m0;
    v0 += __shfl_xor(u1, 2);
    v0 += __shfl_xor(v0, 1);
    int t = r / NN;
    int n = r - t*NN;
    float val = v0 * ns[n];
    unsigned u = f2bf(val) << (b2*16);
    u |= __shfl_xor(u, 2);
    if ((lane & 3) == 0){
      int kk = b8*2 + b4;
      ((unsigned*)h1)[((long long)n*10 + t)*4 + kk] = u;
    }
  }
}

// ======= gather kernels: t-pair mapping =======
// item = n*5 + tp, tp in [0,5); thread owns windows t0=2tp, t0+1 (32 B/edge).
// 4-edge manual unroll: 4 csr reads + 8 independent 16-B gathers in flight.

#define AGG_ITEMS (NN*5)
#define AGG_BLOCKS ((AGG_ITEMS + 255)/256)

// ---------------- aggregate1 + conv1 epilogue (+pre-scale for layer2) ----------------
__global__ __launch_bounds__(256) void k_agg1(const uint4* __restrict__ h1,
                                              const int* __restrict__ row_start,
                                              const int* __restrict__ csr,
                                              const float* __restrict__ ns,
                                              const float* __restrict__ nd,
                                              const float* __restrict__ b1,
                                              uint4* __restrict__ x2p){
  __shared__ float b1s[8];
  int tid = threadIdx.x;
  if (tid < 8) b1s[tid] = b1[tid];
  __syncthreads();
  int item = blockIdx.x*256 + tid;
  if (item >= AGG_ITEMS) return;
  int n  = item / 5;
  int t0 = (item - n*5)*2;
  float acc[16];
  #pragma unroll
  for (int j = 0; j < 16; ++j) acc[j] = 0.f;
  int e0 = row_start[n], e1 = row_start[n+1];
  int e = e0;
  for (; e + 4 <= e1; e += 4){
    int s0 = csr[e], s1 = csr[e+1], s2 = csr[e+2], s3 = csr[e+3];
    uint4 va0 = h1[(long long)s0*10 + t0], vb0 = h1[(long long)s0*10 + t0 + 1];
    uint4 va1 = h1[(long long)s1*10 + t0], vb1 = h1[(long long)s1*10 + t0 + 1];
    uint4 va2 = h1[(long long)s2*10 + t0], vb2 = h1[(long long)s2*10 + t0 + 1];
    uint4 va3 = h1[(long long)s3*10 + t0], vb3 = h1[(long long)s3*10 + t0 + 1];
    #define ACC_A(v) { acc[0]+=bflo(v.x); acc[1]+=bfhi(v.x); acc[2]+=bflo(v.y); acc[3]+=bfhi(v.y); \
                       acc[4]+=bflo(v.z); acc[5]+=bfhi(v.z); acc[6]+=bflo(v.w); acc[7]+=bfhi(v.w); }
    #define ACC_B(v) { acc[8]+=bflo(v.x); acc[9]+=bfhi(v.x); acc[10]+=bflo(v.y); acc[11]+=bfhi(v.y); \
                       acc[12]+=bflo(v.z); acc[13]+=bfhi(v.z); acc[14]+=bflo(v.w); acc[15]+=bfhi(v.w); }
    ACC_A(va0) ACC_B(vb0) ACC_A(va1) ACC_B(vb1)
    ACC_A(va2) ACC_B(vb2) ACC_A(va3) ACC_B(vb3)
  }
  for (; e < e1; ++e){
    int s = csr[e];
    uint4 va = h1[(long long)s*10 + t0], vb = h1[(long long)s*10 + t0 + 1];
    ACC_A(va) ACC_B(vb)
  }
  float sc = nd[n];
  float osc = ns[n];  // layer-2 source-norm pre-scale folded in
  uint4 pka, pkb;
  {
    float o0 = fmaxf(acc[0]*sc + b1s[0], 0.f)*osc;
    float o1 = fmaxf(acc[1]*sc + b1s[1], 0.f)*osc;
    float o2 = fmaxf(acc[2]*sc + b1s[2], 0.f)*osc;
    float o3 = fmaxf(acc[3]*sc + b1s[3], 0.f)*osc;
    float o4 = fmaxf(acc[4]*sc + b1s[4], 0.f)*osc;
    float o5 = fmaxf(acc[5]*sc + b1s[5], 0.f)*osc;
    float o6 = fmaxf(acc[6]*sc + b1s[6], 0.f)*osc;
    float o7 = fmaxf(acc[7]*sc + b1s[7], 0.f)*osc;
    pka.x = pack2(o0,o1); pka.y = pack2(o2,o3); pka.z = pack2(o4,o5); pka.w = pack2(o6,o7);
  }
  {
    float o0 = fmaxf(acc[8]*sc  + b1s[0], 0.f)*osc;
    float o1 = fmaxf(acc[9]*sc  + b1s[1], 0.f)*osc;
    float o2 = fmaxf(acc[10]*sc + b1s[2], 0.f)*osc;
    float o3 = fmaxf(acc[11]*sc + b1s[3], 0.f)*osc;
    float o4 = fmaxf(acc[12]*sc + b1s[4], 0.f)*osc;
    float o5 = fmaxf(acc[13]*sc + b1s[5], 0.f)*osc;
    float o6 = fmaxf(acc[14]*sc + b1s[6], 0.f)*osc;
    float o7 = fmaxf(acc[15]*sc + b1s[7], 0.f)*osc;
    pkb.x = pack2(o0,o1); pkb.y = pack2(o2,o3); pkb.z = pack2(o4,o5); pkb.w = pack2(o6,o7);
  }
  x2p[(long long)n*10 + t0]     = pka;
  x2p[(long long)n*10 + t0 + 1] = pkb;
}

// ---------------- aggregate2 + W2 epilogue + LSTM input projection (bf16 xg) ----------------
__global__ __launch_bounds__(256) void k_agg2(const uint4* __restrict__ x2p,
                                              const int* __restrict__ row_start,
                                              const int* __restrict__ csr,
                                              const float* __restrict__ nd,
                                              const float* __restrict__ W2,
                                              const float* __restrict__ b2,
                                              const float* __restrict__ Wih,
                                              const float* __restrict__ bih,
                                              const float* __restrict__ bhh,
                                              uint4* __restrict__ xg){
  __shared__ float w2[128];     // (8,16) row-major
  __shared__ float4 wih[128];   // (32,16) row-major as float4
  __shared__ float bsum[32];
  __shared__ float b2s[16];
  int tid = threadIdx.x;
  if (tid < 128){ w2[tid] = W2[tid]; wih[tid] = ((const float4*)Wih)[tid]; }
  if (tid < 32) bsum[tid] = bih[tid] + bhh[tid];
  if (tid < 16) b2s[tid] = b2[tid];
  __syncthreads();
  int item = blockIdx.x*256 + tid;
  if (item >= AGG_ITEMS) return;
  int n  = item / 5;
  int t0 = (item - n*5)*2;
  float acc[16];
  #pragma unroll
  for (int j = 0; j < 16; ++j) acc[j] = 0.f;
  int e0 = row_start[n], e1 = row_start[n+1];
  int e = e0;
  for (; e + 4 <= e1; e += 4){
    int s0 = csr[e], s1 = csr[e+1], s2 = csr[e+2], s3 = csr[e+3];
    uint4 va0 = x2p[(long long)s0*10 + t0], vb0 = x2p[(long long)s0*10 + t0 + 1];
    uint4 va1 = x2p[(long long)s1*10 + t0], vb1 = x2p[(long long)s1*10 + t0 + 1];
    uint4 va2 = x2p[(long long)s2*10 + t0], vb2 = x2p[(long long)s2*10 + t0 + 1];
    uint4 va3 = x2p[(long long)s3*10 + t0], vb3 = x2p[(long long)s3*10 + t0 + 1];
    ACC_A(va0) ACC_B(vb0) ACC_A(va1) ACC_B(vb1)
    ACC_A(va2) ACC_B(vb2) ACC_A(va3) ACC_B(vb3)
  }
  for (; e < e1; ++e){
    int s = csr[e];
    uint4 va = x2p[(long long)s*10 + t0], vb = x2p[(long long)s*10 + t0 + 1];
    ACC_A(va) ACC_B(vb)
  }
  float sc = nd[n];
  // two windows sequentially to limit live registers
  #pragma unroll
  for (int half = 0; half < 2; ++half){
    const float* a = &acc[half*8];
    float y[16];
    #pragma unroll
    for (int j = 0; j < 16; ++j){
      float s = 0.f;
      #pragma unroll
      for (int k = 0; k < 8; ++k) s += a[k]*w2[k*16 + j];
      y[j] = fmaxf(s*sc + b2s[j], 0.f);
    }
    uint4* outp = xg + ((long long)n*10 + t0 + half)*4;
    #pragma unroll
    for (int g8 = 0; g8 < 4; ++g8){
      float gv[8];
      #pragma unroll
      for (int c = 0; c < 8; ++c){
        int g = g8*8 + c;
        float s = bsum[g];
        #pragma unroll
        for (int q = 0; q < 4; ++q){
          float4 wv = wih[g*4 + q];
          s += y[q*4+0]*wv.x + y[q*4+1]*wv.y + y[q*4+2]*wv.z + y[q*4+3]*wv.w;
        }
        gv[c] = s;
      }
      uint4 pk;
      pk.x = pack2(gv[0],gv[1]); pk.y = pack2(gv[2],gv[3]);
      pk.z = pack2(gv[4],gv[5]); pk.w = pack2(gv[6],gv[7]);
      outp[g8] = pk;
    }
  }
}

// ---------------- LSTM over T=10 + max-pool reduce ----------------
__global__ __launch_bounds__(256) void k_lstm(const uint4* __restrict__ xg,
                                              const float* __restrict__ Whh,
                                              unsigned* __restrict__ maxbuf){
  __shared__ float4 whh[64];   // (32,8) row-major as float4: whh[g*2+q]
  __shared__ unsigned smax[8];
  int tid = threadIdx.x;
  if (tid < 64) whh[tid] = ((const float4*)Whh)[tid];
  if (tid < 8) smax[tid] = 0u;
  __syncthreads();
  int n = blockIdx.x*256 + tid;
  if (n < NN){
    float h[8] = {0,0,0,0,0,0,0,0};
    float c[8] = {0,0,0,0,0,0,0,0};
    const uint4* xr = xg + (long long)n*40; // [t][4 uint4] contiguous per node
    for (int t = 0; t < TW; ++t){
      float g[32];
      #pragma unroll
      for (int q = 0; q < 4; ++q){
        uint4 v = xr[t*4 + q];
        g[q*8+0]=bflo(v.x); g[q*8+1]=bfhi(v.x);
        g[q*8+2]=bflo(v.y); g[q*8+3]=bfhi(v.y);
        g[q*8+4]=bflo(v.z); g[q*8+5]=bfhi(v.z);
        g[q*8+6]=bflo(v.w); g[q*8+7]=bfhi(v.w);
      }
      #pragma unroll
      for (int gi = 0; gi < 32; ++gi){
        float4 wa = whh[gi*2+0], wb = whh[gi*2+1];
        g[gi] += h[0]*wa.x + h[1]*wa.y + h[2]*wa.z + h[3]*wa.w
               + h[4]*wb.x + h[5]*wb.y + h[6]*wb.z + h[7]*wb.w;
      }
      #pragma unroll
      for (int j = 0; j < 8; ++j){
        float ig = sigf(g[j]);
        float fg = sigf(g[8+j]);
        float gg = tanhfast(g[16+j]);
        float og = sigf(g[24+j]);
        c[j] = fg*c[j] + ig*gg;
        h[j] = og*tanhfast(c[j]);
      }
    }
    #pragma unroll
    for (int j = 0; j < 8; ++j){
      unsigned b = __float_as_uint(h[j]);
      unsigned u = (b & 0x80000000u) ? ~b : (b | 0x80000000u); // monotonic map
      atomicMax(&smax[j], u);
    }
  }
  __syncthreads();
  if (tid < 8) atomicMax(&maxbuf[tid], smax[tid]);
}

// ---------------- head ----------------
__global__ void k_final(const unsigned* __restrict__ maxbuf,
                        const float* __restrict__ Wo, const float* __restrict__ bo,
                        float* __restrict__ out){
  if (blockIdx.x == 0 && threadIdx.x == 0){
    float m[8];
    #pragma unroll
    for (int j = 0; j < 8; ++j){
      unsigned u = maxbuf[j];
      unsigned b = (u & 0x80000000u) ? (u ^ 0x80000000u) : ~u;
      m[j] = __uint_as_float(b);
    }
    #pragma unroll
    for (int o = 0; o < 4; ++o){
      float s = bo[o];
      #pragma unroll
      for (int k = 0; k < 8; ++k) s += m[k]*Wo[k*4 + o];
      out[o] = 1.0f/(1.0f + __expf(-s));
    }
  }
}

extern "C" void kernel_launch(void* const* d_in, const int* in_sizes, int n_in,
                              void* d_out, int out_size, void* d_ws, size_t ws_size,
                              hipStream_t stream) {
  const float* feat = (const float*)d_in[0];
  const int*   src  = (const int*)d_in[1];
  const int*   dst  = (const int*)d_in[2];
  const float* W1   = (const float*)d_in[3];
  const float* b1   = (const float*)d_in[4];
  const float* W2   = (const float*)d_in[5];
  const float* b2   = (const float*)d_in[6];
  const float* Wih  = (const float*)d_in[7];
  const float* Whh  = (const float*)d_in[8];
  const float* bih  = (const float*)d_in[9];
  const float* bhh  = (const float*)d_in[10];
  const float* Wo   = (const float*)d_in[11];
  const float* bo   = (const float*)d_in[12];
  float* out = (float*)d_out;

  // workspace layout
  const size_t SN = 50048; // padded node stride
  int*      dego      = (int*)d_ws;
  int*      degi      = dego + SN;
  int*      cursor    = degi + SN;
  float*    ns        = (float*)(cursor + SN);
  float*    nd        = ns + SN;
  int*      row_start = (int*)(nd + SN);       // 50001 used, 50304 reserved
  int*      bsum      = row_start + 50304;     // 128
  unsigned* maxbuf    = (unsigned*)(bsum + 128); // 8 used, 64 reserved
  int*      csr       = (int*)(maxbuf + 64);   // 800000
  uint4*    h1        = (uint4*)(csr + 800000);   // 500,000 uint4 = 8 MB  [n][t]
  uint4*    x2p       = h1 + 500000;              // 500,000 uint4 = 8 MB  [n][t]
  uint4*    xg        = x2p + 500000;             // 2,000,000 uint4 = 32 MB [n][t][4]

  hipMemsetAsync(dego, 0, 3*SN*sizeof(int), stream);

  const int B = 256;
  k_degree<<<(NE + B - 1)/B, B, 0, stream>>>(src, dst, dego, degi);

  const int NB = (NN + 511)/512; // 98
  k_scan1n<<<NB, 512, 0, stream>>>(degi, dego, bsum, ns, nd, maxbuf);
  k_scan2<<<1, 64, 0, stream>>>(bsum, NB, row_start);
  k_scan3<<<NB, 512, 0, stream>>>(degi, bsum, row_start);
  k_fill <<<(NE + B - 1)/B, B, 0, stream>>>(src, dst, row_start, cursor, csr);

  k_conv1<<<CONV1_BLOCKS, B, 0, stream>>>(feat, W1, ns, h1);
  k_agg1 <<<AGG_BLOCKS, B, 0, stream>>>(h1, row_start, csr, ns, nd, b1, x2p);
  k_agg2 <<<AGG_BLOCKS, B, 0, stream>>>(x2p, row_start, csr, nd, W2, b2, Wih, bih, bhh, xg);
  k_lstm <<<(NN + B - 1)/B, B, 0, stream>>>(xg, Whh, maxbuf);
  k_final<<<1, 64, 0, stream>>>(maxbuf, Wo, bo, out);
}

// Round 8
// 322.045 us; speedup vs baseline: 1.9439x; 1.9439x over previous
//
#include <hip/hip_runtime.h>
#include <math.h>

#define NN 50000
#define NE 800000
#define TW 10

static __device__ __forceinline__ float sigf(float x){ return 1.0f/(1.0f+__expf(-x)); }
static __device__ __forceinline__ float tanhfast(float x){
  float e2 = __expf(2.0f*x);
  return 1.0f - 2.0f/(e2 + 1.0f);
}
// bf16 pack/unpack (RNE)
static __device__ __forceinline__ unsigned f2bf(float f){
  unsigned u = __float_as_uint(f);
  return (u + 0x7FFFu + ((u>>16)&1u)) >> 16;
}
static __device__ __forceinline__ unsigned pack2(float a, float b){
  return f2bf(a) | (f2bf(b) << 16);
}
static __device__ __forceinline__ float bflo(unsigned u){ return __uint_as_float(u << 16); }
static __device__ __forceinline__ float bfhi(unsigned u){ return __uint_as_float(u & 0xFFFF0000u); }

// ---------------- degree ----------------
__global__ void k_degree(const int* __restrict__ src, const int* __restrict__ dst,
                         int* __restrict__ dego, int* __restrict__ degi){
  int e = blockIdx.x*256 + threadIdx.x;
  if (e < NE){
    atomicAdd(&dego[src[e]], 1);
    atomicAdd(&degi[dst[e]], 1);
  }
}

// ---------------- scan block-sum + norms (fused) ----------------
__global__ void k_scan1n(const int* __restrict__ degi, const int* __restrict__ dego,
                         int* __restrict__ bsum, float* __restrict__ ns,
                         float* __restrict__ nd, unsigned* __restrict__ maxbuf){
  __shared__ int s[512];
  int i = blockIdx.x*512 + threadIdx.x;
  int v = (i < NN) ? degi[i] : 0;
  s[threadIdx.x] = v;
  if (i < NN){
    int a = dego[i]; if (a < 1) a = 1;
    int b = v;       if (b < 1) b = 1;
    ns[i] = rsqrtf((float)a);
    nd[i] = rsqrtf((float)b);
  }
  if (blockIdx.x == 0 && threadIdx.x < 8) maxbuf[threadIdx.x] = 0x3FFFFFFFu; // map(-2.0f)
  __syncthreads();
  for (int st = 256; st > 0; st >>= 1){
    if (threadIdx.x < st) s[threadIdx.x] += s[threadIdx.x + st];
    __syncthreads();
  }
  if (threadIdx.x == 0) bsum[blockIdx.x] = s[0];
}

// ---------------- scan3: per-block offset computed in-kernel (scan2 folded in) ----------------
__global__ void k_scan3(const int* __restrict__ degi, const int* __restrict__ bsum,
                        int* __restrict__ row_start){
  __shared__ int s[512];
  __shared__ int boff;
  int tid = threadIdx.x;
  int i = blockIdx.x*512 + tid;
  int v = (i < NN) ? degi[i] : 0;
  s[tid] = v;
  if (tid == 0){
    int run = 0;
    for (int b = 0; b < blockIdx.x; ++b) run += bsum[b];
    boff = run;
    if (blockIdx.x == 0) row_start[NN] = NE;
  }
  __syncthreads();
  for (int st = 1; st < 512; st <<= 1){
    int add = (tid >= st) ? s[tid - st] : 0;
    __syncthreads();
    s[tid] += add;
    __syncthreads();
  }
  if (i < NN) row_start[i] = boff + s[tid] - v; // exclusive
}

__global__ void k_fill(const int* __restrict__ src, const int* __restrict__ dst,
                       const int* __restrict__ row_start, int* __restrict__ cursor,
                       int* __restrict__ csr){
  int e = blockIdx.x*256 + threadIdx.x;
  if (e < NE){
    int d = dst[e];
    int p = atomicAdd(&cursor[d], 1);
    csr[row_start[d] + p] = src[e];
  }
}

// ---------------- conv1: h1[n][t] = bf16( (feat[t][n]) @ W1 * ns[n] ) ----------------
// 16 lanes cooperate per row (R6 form — measured good).
#define CONV1_BLOCKS 2000
__global__ __launch_bounds__(256) void k_conv1(const float* __restrict__ feat,
                                               const float* __restrict__ W1,
                                               const float* __restrict__ ns,
                                               uint4* __restrict__ h1){
  __shared__ float4 w[256];
  int tid = threadIdx.x;
  w[tid] = ((const float4*)W1)[tid];
  __syncthreads();
  int lane = tid & 15;
  float4 wa[8], wb[8];
  #pragma unroll
  for (int d = 0; d < 8; ++d){
    wa[d] = w[(lane*8 + d)*2 + 0];
    wb[d] = w[(lane*8 + d)*2 + 1];
  }
  int gid = (blockIdx.x*256 + tid) >> 4;
  const int ngroups = CONV1_BLOCKS*16;
  for (int r = gid; r < TW*NN; r += ngroups){
    const float4* frow = (const float4*)feat + (long long)r*32 + lane*2;
    float4 f0 = frow[0], f1 = frow[1];
    float fs[8] = {f0.x,f0.y,f0.z,f0.w,f1.x,f1.y,f1.z,f1.w};
    float acc[8] = {0,0,0,0,0,0,0,0};
    #pragma unroll
    for (int d = 0; d < 8; ++d){
      float fv = fs[d];
      acc[0] += fv*wa[d].x; acc[1] += fv*wa[d].y; acc[2] += fv*wa[d].z; acc[3] += fv*wa[d].w;
      acc[4] += fv*wb[d].x; acc[5] += fv*wb[d].y; acc[6] += fv*wb[d].z; acc[7] += fv*wb[d].w;
    }
    int b8 = (lane>>3)&1, b4 = (lane>>2)&1, b2 = (lane>>1)&1;
    float s0 = b8 ? acc[0] : acc[4], s1 = b8 ? acc[1] : acc[5];
    float s2 = b8 ? acc[2] : acc[6], s3 = b8 ? acc[3] : acc[7];
    float k0 = b8 ? acc[4] : acc[0], k1 = b8 ? acc[5] : acc[1];
    float k2 = b8 ? acc[6] : acc[2], k3 = b8 ? acc[7] : acc[3];
    k0 += __shfl_xor(s0, 8); k1 += __shfl_xor(s1, 8);
    k2 += __shfl_xor(s2, 8); k3 += __shfl_xor(s3, 8);
    float t0 = b4 ? k0 : k2, t1 = b4 ? k1 : k3;
    float m0 = b4 ? k2 : k0, m1 = b4 ? k3 : k1;
    m0 += __shfl_xor(t0, 4); m1 += __shfl_xor(t1, 4);
    float u1 = b2 ? m0 : m1;
    float v0 = b2 ? m1 : m0;
    v0 += __shfl_xor(u1, 2);
    v0 += __shfl_xor(v0, 1);
    int t = r / NN;
    int n = r - t*NN;
    float val = v0 * ns[n];
    unsigned u = f2bf(val) << (b2*16);
    u |= __shfl_xor(u, 2);
    if ((lane & 3) == 0){
      int kk = b8*2 + b4;
      ((unsigned*)h1)[((long long)n*10 + t)*4 + kk] = u;
    }
  }
}

// ======= gather kernels (R6 form): block = 25 nodes x 10 windows =======
// n = blk*25 + tid/10; t = tid%10.  h1/x2p: [n][t] -> uint4 (8 bf16, 16 B).

// ---------------- aggregate1 + conv1 epilogue (+pre-scale for layer2) ----------------
__global__ __launch_bounds__(256) void k_agg1(const uint4* __restrict__ h1,
                                              const int* __restrict__ row_start,
                                              const int* __restrict__ csr,
                                              const float* __restrict__ ns,
                                              const float* __restrict__ nd,
                                              const float* __restrict__ b1,
                                              uint4* __restrict__ x2p){
  __shared__ float b1s[8];
  int tid = threadIdx.x;
  if (tid < 8) b1s[tid] = b1[tid];
  __syncthreads();
  if (tid >= 250) return;
  int n = blockIdx.x*25 + tid/10;
  int t = tid - (tid/10)*10;
  float a0=0,a1=0,a2=0,a3=0,a4=0,a5=0,a6=0,a7=0;
  int e0 = row_start[n], e1 = row_start[n+1];
  for (int e = e0; e < e1; ++e){
    int s = csr[e];
    uint4 v = h1[(long long)s*10 + t];
    a0 += bflo(v.x); a1 += bfhi(v.x);
    a2 += bflo(v.y); a3 += bfhi(v.y);
    a4 += bflo(v.z); a5 += bfhi(v.z);
    a6 += bflo(v.w); a7 += bfhi(v.w);
  }
  float sc = nd[n];
  float osc = ns[n];  // layer-2 source-norm pre-scale folded in
  float o0 = fmaxf(a0*sc + b1s[0], 0.f)*osc;
  float o1 = fmaxf(a1*sc + b1s[1], 0.f)*osc;
  float o2 = fmaxf(a2*sc + b1s[2], 0.f)*osc;
  float o3 = fmaxf(a3*sc + b1s[3], 0.f)*osc;
  float o4 = fmaxf(a4*sc + b1s[4], 0.f)*osc;
  float o5 = fmaxf(a5*sc + b1s[5], 0.f)*osc;
  float o6 = fmaxf(a6*sc + b1s[6], 0.f)*osc;
  float o7 = fmaxf(a7*sc + b1s[7], 0.f)*osc;
  uint4 pk;
  pk.x = pack2(o0,o1); pk.y = pack2(o2,o3); pk.z = pack2(o4,o5); pk.w = pack2(o6,o7);
  x2p[(long long)n*10 + t] = pk;
}

// ---------------- aggregate2 + W2 epilogue + LSTM input projection (bf16 xg) ----------------
__global__ __launch_bounds__(256) void k_agg2(const uint4* __restrict__ x2p,
                                              const int* __restrict__ row_start,
                                              const int* __restrict__ csr,
                                              const float* __restrict__ nd,
                                              const float* __restrict__ W2,
                                              const float* __restrict__ b2,
                                              const float* __restrict__ Wih,
                                              const float* __restrict__ bih,
                                              const float* __restrict__ bhh,
                                              uint4* __restrict__ xg){
  __shared__ float w2[128];     // (8,16) row-major
  __shared__ float4 wih[128];   // (32,16) row-major as float4
  __shared__ float bsum[32];
  __shared__ float b2s[16];
  int tid = threadIdx.x;
  if (tid < 128){ w2[tid] = W2[tid]; wih[tid] = ((const float4*)Wih)[tid]; }
  if (tid < 32) bsum[tid] = bih[tid] + bhh[tid];
  if (tid < 16) b2s[tid] = b2[tid];
  __syncthreads();
  if (tid >= 250) return;
  int nl = tid/10;
  int t  = tid - nl*10;
  int n = blockIdx.x*25 + nl;
  float acc[8] = {0,0,0,0,0,0,0,0};
  int e0 = row_start[n], e1 = row_start[n+1];
  for (int e = e0; e < e1; ++e){
    int s = csr[e];
    uint4 v = x2p[(long long)s*10 + t];
    acc[0] += bflo(v.x); acc[1] += bfhi(v.x);
    acc[2] += bflo(v.y); acc[3] += bfhi(v.y);
    acc[4] += bflo(v.z); acc[5] += bfhi(v.z);
    acc[6] += bflo(v.w); acc[7] += bfhi(v.w);
  }
  float sc = nd[n];
  float y[16];
  #pragma unroll
  for (int j = 0; j < 16; ++j){
    float s = 0.f;
    #pragma unroll
    for (int k = 0; k < 8; ++k) s += acc[k]*w2[k*16 + j];
    y[j] = fmaxf(s*sc + b2s[j], 0.f);
  }
  // gates g[0..31] = bsum[g] + y . Wih[g][:]  -> packed bf16, 4 x uint4 per (n,t)
  uint4* outp = xg + ((long long)n*10 + t)*4;
  #pragma unroll
  for (int g8 = 0; g8 < 4; ++g8){
    float gv[8];
    #pragma unroll
    for (int c = 0; c < 8; ++c){
      int g = g8*8 + c;
      float s = bsum[g];
      #pragma unroll
      for (int q = 0; q < 4; ++q){
        float4 wv = wih[g*4 + q];
        s += y[q*4+0]*wv.x + y[q*4+1]*wv.y + y[q*4+2]*wv.z + y[q*4+3]*wv.w;
      }
      gv[c] = s;
    }
    uint4 pk;
    pk.x = pack2(gv[0],gv[1]); pk.y = pack2(gv[2],gv[3]);
    pk.z = pack2(gv[4],gv[5]); pk.w = pack2(gv[6],gv[7]);
    outp[g8] = pk;
  }
}

// ---------------- LSTM over T=10 + max-pool reduce + fused head (last block) ----------------
__global__ __launch_bounds__(256) void k_lstm(const uint4* __restrict__ xg,
                                              const float* __restrict__ Whh,
                                              unsigned* __restrict__ maxbuf,
                                              int* __restrict__ done,
                                              const float* __restrict__ Wo,
                                              const float* __restrict__ bo,
                                              float* __restrict__ out,
                                              int nblocks){
  __shared__ float4 whh[64];   // (32,8) row-major as float4: whh[g*2+q]
  __shared__ unsigned smax[8];
  __shared__ int lastflag;
  int tid = threadIdx.x;
  if (tid < 64) whh[tid] = ((const float4*)Whh)[tid];
  if (tid < 8) smax[tid] = 0u;
  __syncthreads();
  int n = blockIdx.x*256 + tid;
  if (n < NN){
    float h[8] = {0,0,0,0,0,0,0,0};
    float c[8] = {0,0,0,0,0,0,0,0};
    const uint4* xr = xg + (long long)n*40; // [t][4 uint4] contiguous per node
    for (int t = 0; t < TW; ++t){
      float g[32];
      #pragma unroll
      for (int q = 0; q < 4; ++q){
        uint4 v = xr[t*4 + q];
        g[q*8+0]=bflo(v.x); g[q*8+1]=bfhi(v.x);
        g[q*8+2]=bflo(v.y); g[q*8+3]=bfhi(v.y);
        g[q*8+4]=bflo(v.z); g[q*8+5]=bfhi(v.z);
        g[q*8+6]=bflo(v.w); g[q*8+7]=bfhi(v.w);
      }
      #pragma unroll
      for (int gi = 0; gi < 32; ++gi){
        float4 wa = whh[gi*2+0], wb = whh[gi*2+1];
        g[gi] += h[0]*wa.x + h[1]*wa.y + h[2]*wa.z + h[3]*wa.w
               + h[4]*wb.x + h[5]*wb.y + h[6]*wb.z + h[7]*wb.w;
      }
      #pragma unroll
      for (int j = 0; j < 8; ++j){
        float ig = sigf(g[j]);
        float fg = sigf(g[8+j]);
        float gg = tanhfast(g[16+j]);
        float og = sigf(g[24+j]);
        c[j] = fg*c[j] + ig*gg;
        h[j] = og*tanhfast(c[j]);
      }
    }
    #pragma unroll
    for (int j = 0; j < 8; ++j){
      unsigned b = __float_as_uint(h[j]);
      unsigned u = (b & 0x80000000u) ? ~b : (b | 0x80000000u); // monotonic map
      atomicMax(&smax[j], u);
    }
  }
  __syncthreads();
  if (tid < 8) atomicMax(&maxbuf[tid], smax[tid]);
  __syncthreads();
  if (tid == 0){
    __threadfence();
    int prev = atomicAdd(done, 1);
    lastflag = (prev == nblocks - 1);
  }
  __syncthreads();
  if (lastflag && tid == 0){
    float m[8];
    #pragma unroll
    for (int j = 0; j < 8; ++j){
      unsigned u = atomicAdd(&maxbuf[j], 0u); // device-coherent read
      unsigned b = (u & 0x80000000u) ? (u ^ 0x80000000u) : ~u;
      m[j] = __uint_as_float(b);
    }
    #pragma unroll
    for (int o = 0; o < 4; ++o){
      float s = bo[o];
      #pragma unroll
      for (int k = 0; k < 8; ++k) s += m[k]*Wo[k*4 + o];
      out[o] = 1.0f/(1.0f + __expf(-s));
    }
  }
}

extern "C" void kernel_launch(void* const* d_in, const int* in_sizes, int n_in,
                              void* d_out, int out_size, void* d_ws, size_t ws_size,
                              hipStream_t stream) {
  const float* feat = (const float*)d_in[0];
  const int*   src  = (const int*)d_in[1];
  const int*   dst  = (const int*)d_in[2];
  const float* W1   = (const float*)d_in[3];
  const float* b1   = (const float*)d_in[4];
  const float* W2   = (const float*)d_in[5];
  const float* b2   = (const float*)d_in[6];
  const float* Wih  = (const float*)d_in[7];
  const float* Whh  = (const float*)d_in[8];
  const float* bih  = (const float*)d_in[9];
  const float* bhh  = (const float*)d_in[10];
  const float* Wo   = (const float*)d_in[11];
  const float* bo   = (const float*)d_in[12];
  float* out = (float*)d_out;

  // workspace layout
  const size_t SN = 50048; // padded node stride
  int*      dego      = (int*)d_ws;
  int*      degi      = dego + SN;
  int*      cursor    = degi + SN;   // cursor[NN..SN) unused -> zeroed scratch
  int*      done      = cursor + 50040; // inside memset region, zeroed each call
  float*    ns        = (float*)(cursor + SN);
  float*    nd        = ns + SN;
  int*      row_start = (int*)(nd + SN);       // 50001 used, 50304 reserved
  int*      bsum      = row_start + 50304;     // 128
  unsigned* maxbuf    = (unsigned*)(bsum + 128); // 8 used, 64 reserved
  int*      csr       = (int*)(maxbuf + 64);   // 800000
  uint4*    h1        = (uint4*)(csr + 800000);   // 500,000 uint4 = 8 MB  [n][t]
  uint4*    x2p       = h1 + 500000;              // 500,000 uint4 = 8 MB  [n][t]
  uint4*    xg        = x2p + 500000;             // 2,000,000 uint4 = 32 MB [n][t][4]

  hipMemsetAsync(dego, 0, 3*SN*sizeof(int), stream);

  const int B = 256;
  k_degree<<<(NE + B - 1)/B, B, 0, stream>>>(src, dst, dego, degi);

  const int NB = (NN + 511)/512; // 98
  k_scan1n<<<NB, 512, 0, stream>>>(degi, dego, bsum, ns, nd, maxbuf);
  k_scan3<<<NB, 512, 0, stream>>>(degi, bsum, row_start);
  k_fill <<<(NE + B - 1)/B, B, 0, stream>>>(src, dst, row_start, cursor, csr);

  k_conv1<<<CONV1_BLOCKS, B, 0, stream>>>(feat, W1, ns, h1);
  const int NBLK = NN/25; // 2000 blocks
  k_agg1 <<<NBLK, B, 0, stream>>>(h1, row_start, csr, ns, nd, b1, x2p);
  k_agg2 <<<NBLK, B, 0, stream>>>(x2p, row_start, csr, nd, W2, b2, Wih, bih, bhh, xg);
  const int LB = (NN + B - 1)/B; // 196
  k_lstm <<<LB, B, 0, stream>>>(xg, Whh, maxbuf, done, Wo, bo, out, LB);
}

// Round 9
// 321.256 us; speedup vs baseline: 1.9487x; 1.0025x over previous
//
#include <hip/hip_runtime.h>
#include <math.h>

#define NN 50000
#define NE 800000
#define TW 10

static __device__ __forceinline__ float sigf(float x){ return 1.0f/(1.0f+__expf(-x)); }
static __device__ __forceinline__ float tanhfast(float x){
  float e2 = __expf(2.0f*x);
  return 1.0f - 2.0f/(e2 + 1.0f);
}
// bf16 pack/unpack (RNE)
static __device__ __forceinline__ unsigned f2bf(float f){
  unsigned u = __float_as_uint(f);
  return (u + 0x7FFFu + ((u>>16)&1u)) >> 16;
}
static __device__ __forceinline__ unsigned pack2(float a, float b){
  return f2bf(a) | (f2bf(b) << 16);
}
static __device__ __forceinline__ float bflo(unsigned u){ return __uint_as_float(u << 16); }
static __device__ __forceinline__ float bfhi(unsigned u){ return __uint_as_float(u & 0xFFFF0000u); }

// ---------------- zero the counter region (replaces pathological hipMemsetAsync) ----------------
#define ZERO_U4 37536   // 3*SN ints = 150144 ints = 37536 uint4 = 600576 B
__global__ void k_zero(uint4* __restrict__ p){
  int i = blockIdx.x*256 + threadIdx.x;
  uint4 z; z.x = 0u; z.y = 0u; z.z = 0u; z.w = 0u;
  if (i < ZERO_U4) p[i] = z;
}

// ---------------- degree ----------------
__global__ void k_degree(const int* __restrict__ src, const int* __restrict__ dst,
                         int* __restrict__ dego, int* __restrict__ degi){
  int e = blockIdx.x*256 + threadIdx.x;
  if (e < NE){
    atomicAdd(&dego[src[e]], 1);
    atomicAdd(&degi[dst[e]], 1);
  }
}

// ---------------- scan block-sum + norms (fused) ----------------
__global__ void k_scan1n(const int* __restrict__ degi, const int* __restrict__ dego,
                         int* __restrict__ bsum, float* __restrict__ ns,
                         float* __restrict__ nd, unsigned* __restrict__ maxbuf){
  __shared__ int s[512];
  int i = blockIdx.x*512 + threadIdx.x;
  int v = (i < NN) ? degi[i] : 0;
  s[threadIdx.x] = v;
  if (i < NN){
    int a = dego[i]; if (a < 1) a = 1;
    int b = v;       if (b < 1) b = 1;
    ns[i] = rsqrtf((float)a);
    nd[i] = rsqrtf((float)b);
  }
  if (blockIdx.x == 0 && threadIdx.x < 8) maxbuf[threadIdx.x] = 0x3FFFFFFFu; // map(-2.0f)
  __syncthreads();
  for (int st = 256; st > 0; st >>= 1){
    if (threadIdx.x < st) s[threadIdx.x] += s[threadIdx.x + st];
    __syncthreads();
  }
  if (threadIdx.x == 0) bsum[blockIdx.x] = s[0];
}

// ---------------- scan3: per-block offset computed in-kernel ----------------
__global__ void k_scan3(const int* __restrict__ degi, const int* __restrict__ bsum,
                        int* __restrict__ row_start){
  __shared__ int s[512];
  __shared__ int boff;
  int tid = threadIdx.x;
  int i = blockIdx.x*512 + tid;
  int v = (i < NN) ? degi[i] : 0;
  s[tid] = v;
  if (tid == 0){
    int run = 0;
    for (int b = 0; b < blockIdx.x; ++b) run += bsum[b];
    boff = run;
    if (blockIdx.x == 0) row_start[NN] = NE;
  }
  __syncthreads();
  for (int st = 1; st < 512; st <<= 1){
    int add = (tid >= st) ? s[tid - st] : 0;
    __syncthreads();
    s[tid] += add;
    __syncthreads();
  }
  if (i < NN) row_start[i] = boff + s[tid] - v; // exclusive
}

__global__ void k_fill(const int* __restrict__ src, const int* __restrict__ dst,
                       const int* __restrict__ row_start, int* __restrict__ cursor,
                       int* __restrict__ csr){
  int e = blockIdx.x*256 + threadIdx.x;
  if (e < NE){
    int d = dst[e];
    int p = atomicAdd(&cursor[d], 1);
    csr[row_start[d] + p] = src[e];
  }
}

// ---------------- conv1: h1[n][t] = bf16( (feat[t][n]) @ W1 * ns[n] ) ----------------
// 16 lanes cooperate per row (R6 form — measured good).
#define CONV1_BLOCKS 2000
__global__ __launch_bounds__(256) void k_conv1(const float* __restrict__ feat,
                                               const float* __restrict__ W1,
                                               const float* __restrict__ ns,
                                               uint4* __restrict__ h1){
  __shared__ float4 w[256];
  int tid = threadIdx.x;
  w[tid] = ((const float4*)W1)[tid];
  __syncthreads();
  int lane = tid & 15;
  float4 wa[8], wb[8];
  #pragma unroll
  for (int d = 0; d < 8; ++d){
    wa[d] = w[(lane*8 + d)*2 + 0];
    wb[d] = w[(lane*8 + d)*2 + 1];
  }
  int gid = (blockIdx.x*256 + tid) >> 4;
  const int ngroups = CONV1_BLOCKS*16;
  for (int r = gid; r < TW*NN; r += ngroups){
    const float4* frow = (const float4*)feat + (long long)r*32 + lane*2;
    float4 f0 = frow[0], f1 = frow[1];
    float fs[8] = {f0.x,f0.y,f0.z,f0.w,f1.x,f1.y,f1.z,f1.w};
    float acc[8] = {0,0,0,0,0,0,0,0};
    #pragma unroll
    for (int d = 0; d < 8; ++d){
      float fv = fs[d];
      acc[0] += fv*wa[d].x; acc[1] += fv*wa[d].y; acc[2] += fv*wa[d].z; acc[3] += fv*wa[d].w;
      acc[4] += fv*wb[d].x; acc[5] += fv*wb[d].y; acc[6] += fv*wb[d].z; acc[7] += fv*wb[d].w;
    }
    int b8 = (lane>>3)&1, b4 = (lane>>2)&1, b2 = (lane>>1)&1;
    float s0 = b8 ? acc[0] : acc[4], s1 = b8 ? acc[1] : acc[5];
    float s2 = b8 ? acc[2] : acc[6], s3 = b8 ? acc[3] : acc[7];
    float k0 = b8 ? acc[4] : acc[0], k1 = b8 ? acc[5] : acc[1];
    float k2 = b8 ? acc[6] : acc[2], k3 = b8 ? acc[7] : acc[3];
    k0 += __shfl_xor(s0, 8); k1 += __shfl_xor(s1, 8);
    k2 += __shfl_xor(s2, 8); k3 += __shfl_xor(s3, 8);
    float t0 = b4 ? k0 : k2, t1 = b4 ? k1 : k3;
    float m0 = b4 ? k2 : k0, m1 = b4 ? k3 : k1;
    m0 += __shfl_xor(t0, 4); m1 += __shfl_xor(t1, 4);
    float u1 = b2 ? m0 : m1;
    float v0 = b2 ? m1 : m0;
    v0 += __shfl_xor(u1, 2);
    v0 += __shfl_xor(v0, 1);
    int t = r / NN;
    int n = r - t*NN;
    float val = v0 * ns[n];
    unsigned u = f2bf(val) << (b2*16);
    u |= __shfl_xor(u, 2);
    if ((lane & 3) == 0){
      int kk = b8*2 + b4;
      ((unsigned*)h1)[((long long)n*10 + t)*4 + kk] = u;
    }
  }
}

// ======= gather kernels: block = 25 nodes x 10 windows =======
// n = blk*25 + tid/10; t = tid%10.  h1/x2p: [n][t] -> uint4 (8 bf16, 16 B).

// ---------------- aggregate1 + conv1 epilogue (+pre-scale for layer2) ----------------
__global__ __launch_bounds__(256) void k_agg1(const uint4* __restrict__ h1,
                                              const int* __restrict__ row_start,
                                              const int* __restrict__ csr,
                                              const float* __restrict__ ns,
                                              const float* __restrict__ nd,
                                              const float* __restrict__ b1,
                                              uint4* __restrict__ x2p){
  __shared__ float b1s[8];
  int tid = threadIdx.x;
  if (tid < 8) b1s[tid] = b1[tid];
  __syncthreads();
  if (tid >= 250) return;
  int n = blockIdx.x*25 + tid/10;
  int t = tid - (tid/10)*10;
  float a0=0,a1=0,a2=0,a3=0,a4=0,a5=0,a6=0,a7=0;
  int e0 = row_start[n], e1 = row_start[n+1];
  for (int e = e0; e < e1; ++e){
    int s = csr[e];
    uint4 v = h1[(long long)s*10 + t];
    a0 += bflo(v.x); a1 += bfhi(v.x);
    a2 += bflo(v.y); a3 += bfhi(v.y);
    a4 += bflo(v.z); a5 += bfhi(v.z);
    a6 += bflo(v.w); a7 += bfhi(v.w);
  }
  float sc = nd[n];
  float osc = ns[n];  // layer-2 source-norm pre-scale folded in
  float o0 = fmaxf(a0*sc + b1s[0], 0.f)*osc;
  float o1 = fmaxf(a1*sc + b1s[1], 0.f)*osc;
  float o2 = fmaxf(a2*sc + b1s[2], 0.f)*osc;
  float o3 = fmaxf(a3*sc + b1s[3], 0.f)*osc;
  float o4 = fmaxf(a4*sc + b1s[4], 0.f)*osc;
  float o5 = fmaxf(a5*sc + b1s[5], 0.f)*osc;
  float o6 = fmaxf(a6*sc + b1s[6], 0.f)*osc;
  float o7 = fmaxf(a7*sc + b1s[7], 0.f)*osc;
  uint4 pk;
  pk.x = pack2(o0,o1); pk.y = pack2(o2,o3); pk.z = pack2(o4,o5); pk.w = pack2(o6,o7);
  x2p[(long long)n*10 + t] = pk;
}

// ---------------- aggregate2 + W2 epilogue + LSTM input projection (bf16 xg) ----------------
__global__ __launch_bounds__(256) void k_agg2(const uint4* __restrict__ x2p,
                                              const int* __restrict__ row_start,
                                              const int* __restrict__ csr,
                                              const float* __restrict__ nd,
                                              const float* __restrict__ W2,
                                              const float* __restrict__ b2,
                                              const float* __restrict__ Wih,
                                              const float* __restrict__ bih,
                                              const float* __restrict__ bhh,
                                              uint4* __restrict__ xg){
  __shared__ float w2[128];     // (8,16) row-major
  __shared__ float4 wih[128];   // (32,16) row-major as float4
  __shared__ float bsum[32];
  __shared__ float b2s[16];
  int tid = threadIdx.x;
  if (tid < 128){ w2[tid] = W2[tid]; wih[tid] = ((const float4*)Wih)[tid]; }
  if (tid < 32) bsum[tid] = bih[tid] + bhh[tid];
  if (tid < 16) b2s[tid] = b2[tid];
  __syncthreads();
  if (tid >= 250) return;
  int nl = tid/10;
  int t  = tid - nl*10;
  int n = blockIdx.x*25 + nl;
  float acc[8] = {0,0,0,0,0,0,0,0};
  int e0 = row_start[n], e1 = row_start[n+1];
  for (int e = e0; e < e1; ++e){
    int s = csr[e];
    uint4 v = x2p[(long long)s*10 + t];
    acc[0] += bflo(v.x); acc[1] += bfhi(v.x);
    acc[2] += bflo(v.y); acc[3] += bfhi(v.y);
    acc[4] += bflo(v.z); acc[5] += bfhi(v.z);
    acc[6] += bflo(v.w); acc[7] += bfhi(v.w);
  }
  float sc = nd[n];
  float y[16];
  #pragma unroll
  for (int j = 0; j < 16; ++j){
    float s = 0.f;
    #pragma unroll
    for (int k = 0; k < 8; ++k) s += acc[k]*w2[k*16 + j];
    y[j] = fmaxf(s*sc + b2s[j], 0.f);
  }
  // gates g[0..31] = bsum[g] + y . Wih[g][:]  -> packed bf16, 4 x uint4 per (n,t)
  uint4* outp = xg + ((long long)n*10 + t)*4;
  #pragma unroll
  for (int g8 = 0; g8 < 4; ++g8){
    float gv[8];
    #pragma unroll
    for (int c = 0; c < 8; ++c){
      int g = g8*8 + c;
      float s = bsum[g];
      #pragma unroll
      for (int q = 0; q < 4; ++q){
        float4 wv = wih[g*4 + q];
        s += y[q*4+0]*wv.x + y[q*4+1]*wv.y + y[q*4+2]*wv.z + y[q*4+3]*wv.w;
      }
      gv[c] = s;
    }
    uint4 pk;
    pk.x = pack2(gv[0],gv[1]); pk.y = pack2(gv[2],gv[3]);
    pk.z = pack2(gv[4],gv[5]); pk.w = pack2(gv[6],gv[7]);
    outp[g8] = pk;
  }
}

// ---------------- LSTM over T=10 + max-pool reduce + fused head (last block) ----------------
__global__ __launch_bounds__(256) void k_lstm(const uint4* __restrict__ xg,
                                              const float* __restrict__ Whh,
                                              unsigned* __restrict__ maxbuf,
                                              int* __restrict__ done,
                                              const float* __restrict__ Wo,
                                              const float* __restrict__ bo,
                                              float* __restrict__ out,
                                              int nblocks){
  __shared__ float4 whh[64];   // (32,8) row-major as float4: whh[g*2+q]
  __shared__ unsigned smax[8];
  __shared__ int lastflag;
  int tid = threadIdx.x;
  if (tid < 64) whh[tid] = ((const float4*)Whh)[tid];
  if (tid < 8) smax[tid] = 0u;
  __syncthreads();
  int n = blockIdx.x*256 + tid;
  if (n < NN){
    float h[8] = {0,0,0,0,0,0,0,0};
    float c[8] = {0,0,0,0,0,0,0,0};
    const uint4* xr = xg + (long long)n*40; // [t][4 uint4] contiguous per node
    for (int t = 0; t < TW; ++t){
      float g[32];
      #pragma unroll
      for (int q = 0; q < 4; ++q){
        uint4 v = xr[t*4 + q];
        g[q*8+0]=bflo(v.x); g[q*8+1]=bfhi(v.x);
        g[q*8+2]=bflo(v.y); g[q*8+3]=bfhi(v.y);
        g[q*8+4]=bflo(v.z); g[q*8+5]=bfhi(v.z);
        g[q*8+6]=bflo(v.w); g[q*8+7]=bfhi(v.w);
      }
      #pragma unroll
      for (int gi = 0; gi < 32; ++gi){
        float4 wa = whh[gi*2+0], wb = whh[gi*2+1];
        g[gi] += h[0]*wa.x + h[1]*wa.y + h[2]*wa.z + h[3]*wa.w
               + h[4]*wb.x + h[5]*wb.y + h[6]*wb.z + h[7]*wb.w;
      }
      #pragma unroll
      for (int j = 0; j < 8; ++j){
        float ig = sigf(g[j]);
        float fg = sigf(g[8+j]);
        float gg = tanhfast(g[16+j]);
        float og = sigf(g[24+j]);
        c[j] = fg*c[j] + ig*gg;
        h[j] = og*tanhfast(c[j]);
      }
    }
    #pragma unroll
    for (int j = 0; j < 8; ++j){
      unsigned b = __float_as_uint(h[j]);
      unsigned u = (b & 0x80000000u) ? ~b : (b | 0x80000000u); // monotonic map
      atomicMax(&smax[j], u);
    }
  }
  __syncthreads();
  if (tid < 8) atomicMax(&maxbuf[tid], smax[tid]);
  __syncthreads();
  if (tid == 0){
    __threadfence();
    int prev = atomicAdd(done, 1);
    lastflag = (prev == nblocks - 1);
  }
  __syncthreads();
  if (lastflag && tid == 0){
    float m[8];
    #pragma unroll
    for (int j = 0; j < 8; ++j){
      unsigned u = atomicAdd(&maxbuf[j], 0u); // device-coherent read
      unsigned b = (u & 0x80000000u) ? (u ^ 0x80000000u) : ~u;
      m[j] = __uint_as_float(b);
    }
    #pragma unroll
    for (int o = 0; o < 4; ++o){
      float s = bo[o];
      #pragma unroll
      for (int k = 0; k < 8; ++k) s += m[k]*Wo[k*4 + o];
      out[o] = 1.0f/(1.0f + __expf(-s));
    }
  }
}

extern "C" void kernel_launch(void* const* d_in, const int* in_sizes, int n_in,
                              void* d_out, int out_size, void* d_ws, size_t ws_size,
                              hipStream_t stream) {
  const float* feat = (const float*)d_in[0];
  const int*   src  = (const int*)d_in[1];
  const int*   dst  = (const int*)d_in[2];
  const float* W1   = (const float*)d_in[3];
  const float* b1   = (const float*)d_in[4];
  const float* W2   = (const float*)d_in[5];
  const float* b2   = (const float*)d_in[6];
  const float* Wih  = (const float*)d_in[7];
  const float* Whh  = (const float*)d_in[8];
  const float* bih  = (const float*)d_in[9];
  const float* bhh  = (const float*)d_in[10];
  const float* Wo   = (const float*)d_in[11];
  const float* bo   = (const float*)d_in[12];
  float* out = (float*)d_out;

  // workspace layout
  const size_t SN = 50048; // padded node stride
  int*      dego      = (int*)d_ws;
  int*      degi      = dego + SN;
  int*      cursor    = degi + SN;   // cursor[NN..SN) unused -> zeroed scratch
  int*      done      = cursor + 50040; // inside zeroed region
  float*    ns        = (float*)(cursor + SN);
  float*    nd        = ns + SN;
  int*      row_start = (int*)(nd + SN);       // 50001 used, 50304 reserved
  int*      bsum      = row_start + 50304;     // 128
  unsigned* maxbuf    = (unsigned*)(bsum + 128); // 8 used, 64 reserved
  int*      csr       = (int*)(maxbuf + 64);   // 800000
  uint4*    h1        = (uint4*)(csr + 800000);   // 500,000 uint4 = 8 MB  [n][t]
  uint4*    x2p       = h1 + 500000;              // 500,000 uint4 = 8 MB  [n][t]
  uint4*    xg        = x2p + 500000;             // 2,000,000 uint4 = 32 MB [n][t][4]

  const int B = 256;
  k_zero  <<<(ZERO_U4 + B - 1)/B, B, 0, stream>>>((uint4*)d_ws);
  k_degree<<<(NE + B - 1)/B, B, 0, stream>>>(src, dst, dego, degi);

  const int NB = (NN + 511)/512; // 98
  k_scan1n<<<NB, 512, 0, stream>>>(degi, dego, bsum, ns, nd, maxbuf);
  k_scan3<<<NB, 512, 0, stream>>>(degi, bsum, row_start);
  k_fill <<<(NE + B - 1)/B, B, 0, stream>>>(src, dst, row_start, cursor, csr);

  k_conv1<<<CONV1_BLOCKS, B, 0, stream>>>(feat, W1, ns, h1);
  const int NBLK = NN/25; // 2000 blocks
  k_agg1 <<<NBLK, B, 0, stream>>>(h1, row_start, csr, ns, nd, b1, x2p);
  k_agg2 <<<NBLK, B, 0, stream>>>(x2p, row_start, csr, nd, W2, b2, Wih, bih, bhh, xg);
  const int LB = (NN + B - 1)/B; // 196
  k_lstm <<<LB, B, 0, stream>>>(xg, Whh, maxbuf, done, Wo, bo, out, LB);
}

// Round 10
// 312.022 us; speedup vs baseline: 2.0064x; 1.0296x over previous
//
#include <hip/hip_runtime.h>
#include <math.h>

#define NN 50000
#define NE 800000
#define TW 10

static __device__ __forceinline__ float sigf(float x){ return 1.0f/(1.0f+__expf(-x)); }
static __device__ __forceinline__ float tanhfast(float x){
  float e2 = __expf(2.0f*x);
  return 1.0f - 2.0f/(e2 + 1.0f);
}
// bf16 pack/unpack (RNE)
static __device__ __forceinline__ unsigned f2bf(float f){
  unsigned u = __float_as_uint(f);
  return (u + 0x7FFFu + ((u>>16)&1u)) >> 16;
}
static __device__ __forceinline__ unsigned pack2(float a, float b){
  return f2bf(a) | (f2bf(b) << 16);
}
static __device__ __forceinline__ float bflo(unsigned u){ return __uint_as_float(u << 16); }
static __device__ __forceinline__ float bfhi(unsigned u){ return __uint_as_float(u & 0xFFFF0000u); }

// ---------------- zero the counter region ----------------
#define ZERO_U4 37536   // 3*SN ints = 600576 B
__global__ void k_zero(uint4* __restrict__ p){
  int i = blockIdx.x*256 + threadIdx.x;
  uint4 z; z.x = 0u; z.y = 0u; z.z = 0u; z.w = 0u;
  if (i < ZERO_U4) p[i] = z;
}

// ---------------- degree ----------------
__global__ void k_degree(const int* __restrict__ src, const int* __restrict__ dst,
                         int* __restrict__ dego, int* __restrict__ degi){
  int e = blockIdx.x*256 + threadIdx.x;
  if (e < NE){
    atomicAdd(&dego[src[e]], 1);
    atomicAdd(&degi[dst[e]], 1);
  }
}

// ---------------- scan block-sum + norms (fused) ----------------
__global__ void k_scan1n(const int* __restrict__ degi, const int* __restrict__ dego,
                         int* __restrict__ bsum, float* __restrict__ ns,
                         float* __restrict__ nd, unsigned* __restrict__ maxbuf){
  __shared__ int s[512];
  int i = blockIdx.x*512 + threadIdx.x;
  int v = (i < NN) ? degi[i] : 0;
  s[threadIdx.x] = v;
  if (i < NN){
    int a = dego[i]; if (a < 1) a = 1;
    int b = v;       if (b < 1) b = 1;
    ns[i] = rsqrtf((float)a);
    nd[i] = rsqrtf((float)b);
  }
  if (blockIdx.x == 0 && threadIdx.x < 8) maxbuf[threadIdx.x] = 0x3FFFFFFFu; // map(-2.0f)
  __syncthreads();
  for (int st = 256; st > 0; st >>= 1){
    if (threadIdx.x < st) s[threadIdx.x] += s[threadIdx.x + st];
    __syncthreads();
  }
  if (threadIdx.x == 0) bsum[blockIdx.x] = s[0];
}

// ---------------- scan3: per-block offset computed in-kernel ----------------
__global__ void k_scan3(const int* __restrict__ degi, const int* __restrict__ bsum,
                        int* __restrict__ row_start){
  __shared__ int s[512];
  __shared__ int boff;
  int tid = threadIdx.x;
  int i = blockIdx.x*512 + tid;
  int v = (i < NN) ? degi[i] : 0;
  s[tid] = v;
  if (tid == 0){
    int run = 0;
    for (int b = 0; b < blockIdx.x; ++b) run += bsum[b];
    boff = run;
    if (blockIdx.x == 0) row_start[NN] = NE;
  }
  __syncthreads();
  for (int st = 1; st < 512; st <<= 1){
    int add = (tid >= st) ? s[tid - st] : 0;
    __syncthreads();
    s[tid] += add;
    __syncthreads();
  }
  if (i < NN) row_start[i] = boff + s[tid] - v; // exclusive
}

__global__ void k_fill(const int* __restrict__ src, const int* __restrict__ dst,
                       const int* __restrict__ row_start, int* __restrict__ cursor,
                       int* __restrict__ csr){
  int e = blockIdx.x*256 + threadIdx.x;
  if (e < NE){
    int d = dst[e];
    int p = atomicAdd(&cursor[d], 1);
    csr[row_start[d] + p] = src[e];
  }
}

// ---------------- conv1 (R6 form — measured good) ----------------
#define CONV1_BLOCKS 2000
__global__ __launch_bounds__(256) void k_conv1(const float* __restrict__ feat,
                                               const float* __restrict__ W1,
                                               const float* __restrict__ ns,
                                               uint4* __restrict__ h1){
  __shared__ float4 w[256];
  int tid = threadIdx.x;
  w[tid] = ((const float4*)W1)[tid];
  __syncthreads();
  int lane = tid & 15;
  float4 wa[8], wb[8];
  #pragma unroll
  for (int d = 0; d < 8; ++d){
    wa[d] = w[(lane*8 + d)*2 + 0];
    wb[d] = w[(lane*8 + d)*2 + 1];
  }
  int gid = (blockIdx.x*256 + tid) >> 4;
  const int ngroups = CONV1_BLOCKS*16;
  for (int r = gid; r < TW*NN; r += ngroups){
    const float4* frow = (const float4*)feat + (long long)r*32 + lane*2;
    float4 f0 = frow[0], f1 = frow[1];
    float fs[8] = {f0.x,f0.y,f0.z,f0.w,f1.x,f1.y,f1.z,f1.w};
    float acc[8] = {0,0,0,0,0,0,0,0};
    #pragma unroll
    for (int d = 0; d < 8; ++d){
      float fv = fs[d];
      acc[0] += fv*wa[d].x; acc[1] += fv*wa[d].y; acc[2] += fv*wa[d].z; acc[3] += fv*wa[d].w;
      acc[4] += fv*wb[d].x; acc[5] += fv*wb[d].y; acc[6] += fv*wb[d].z; acc[7] += fv*wb[d].w;
    }
    int b8 = (lane>>3)&1, b4 = (lane>>2)&1, b2 = (lane>>1)&1;
    float s0 = b8 ? acc[0] : acc[4], s1 = b8 ? acc[1] : acc[5];
    float s2 = b8 ? acc[2] : acc[6], s3 = b8 ? acc[3] : acc[7];
    float k0 = b8 ? acc[4] : acc[0], k1 = b8 ? acc[5] : acc[1];
    float k2 = b8 ? acc[6] : acc[2], k3 = b8 ? acc[7] : acc[3];
    k0 += __shfl_xor(s0, 8); k1 += __shfl_xor(s1, 8);
    k2 += __shfl_xor(s2, 8); k3 += __shfl_xor(s3, 8);
    float t0 = b4 ? k0 : k2, t1 = b4 ? k1 : k3;
    float m0 = b4 ? k2 : k0, m1 = b4 ? k3 : k1;
    m0 += __shfl_xor(t0, 4); m1 += __shfl_xor(t1, 4);
    float u1 = b2 ? m0 : m1;
    float v0 = b2 ? m1 : m0;
    v0 += __shfl_xor(u1, 2);
    v0 += __shfl_xor(v0, 1);
    int t = r / NN;
    int n = r - t*NN;
    float val = v0 * ns[n];
    unsigned u = f2bf(val) << (b2*16);
    u |= __shfl_xor(u, 2);
    if ((lane & 3) == 0){
      int kk = b8*2 + b4;
      ((unsigned*)h1)[((long long)n*10 + t)*4 + kk] = u;
    }
  }
}

// ======= gather kernels: block = 25 nodes x 10 windows, 4-edge unrolled =======
// n = blk*25 + tid/10; t = tid%10.  acc stays 8 floats; 4 csr reads + 4
// independent 16-B gathers in flight (register-budgeted MLP, no acc[16],
// no runtime-indexed pointers — the R7 spill triggers).

#define ACC8(v) { a0 += bflo(v.x); a1 += bfhi(v.x); a2 += bflo(v.y); a3 += bfhi(v.y); \
                  a4 += bflo(v.z); a5 += bfhi(v.z); a6 += bflo(v.w); a7 += bfhi(v.w); }

// ---------------- aggregate1 + conv1 epilogue (+pre-scale for layer2) ----------------
__global__ __launch_bounds__(256) void k_agg1(const uint4* __restrict__ h1,
                                              const int* __restrict__ row_start,
                                              const int* __restrict__ csr,
                                              const float* __restrict__ ns,
                                              const float* __restrict__ nd,
                                              const float* __restrict__ b1,
                                              uint4* __restrict__ x2p){
  __shared__ float b1s[8];
  int tid = threadIdx.x;
  if (tid < 8) b1s[tid] = b1[tid];
  __syncthreads();
  if (tid >= 250) return;
  int n = blockIdx.x*25 + tid/10;
  int t = tid - (tid/10)*10;
  float a0=0,a1=0,a2=0,a3=0,a4=0,a5=0,a6=0,a7=0;
  int e0 = row_start[n], e1 = row_start[n+1];
  int e = e0;
  for (; e + 4 <= e1; e += 4){
    int s0 = csr[e], s1 = csr[e+1], s2 = csr[e+2], s3 = csr[e+3];
    uint4 v0 = h1[(long long)s0*10 + t];
    uint4 v1 = h1[(long long)s1*10 + t];
    uint4 v2 = h1[(long long)s2*10 + t];
    uint4 v3 = h1[(long long)s3*10 + t];
    ACC8(v0) ACC8(v1) ACC8(v2) ACC8(v3)
  }
  for (; e < e1; ++e){
    int s = csr[e];
    uint4 v = h1[(long long)s*10 + t];
    ACC8(v)
  }
  float sc = nd[n];
  float osc = ns[n];  // layer-2 source-norm pre-scale folded in
  float o0 = fmaxf(a0*sc + b1s[0], 0.f)*osc;
  float o1 = fmaxf(a1*sc + b1s[1], 0.f)*osc;
  float o2 = fmaxf(a2*sc + b1s[2], 0.f)*osc;
  float o3 = fmaxf(a3*sc + b1s[3], 0.f)*osc;
  float o4 = fmaxf(a4*sc + b1s[4], 0.f)*osc;
  float o5 = fmaxf(a5*sc + b1s[5], 0.f)*osc;
  float o6 = fmaxf(a6*sc + b1s[6], 0.f)*osc;
  float o7 = fmaxf(a7*sc + b1s[7], 0.f)*osc;
  uint4 pk;
  pk.x = pack2(o0,o1); pk.y = pack2(o2,o3); pk.z = pack2(o4,o5); pk.w = pack2(o6,o7);
  x2p[(long long)n*10 + t] = pk;
}

// ---------------- aggregate2 + W2 epilogue + LSTM input projection (bf16 xg) ----------------
__global__ __launch_bounds__(256) void k_agg2(const uint4* __restrict__ x2p,
                                              const int* __restrict__ row_start,
                                              const int* __restrict__ csr,
                                              const float* __restrict__ nd,
                                              const float* __restrict__ W2,
                                              const float* __restrict__ b2,
                                              const float* __restrict__ Wih,
                                              const float* __restrict__ bih,
                                              const float* __restrict__ bhh,
                                              uint4* __restrict__ xg){
  __shared__ float w2[128];     // (8,16) row-major
  __shared__ float4 wih[128];   // (32,16) row-major as float4
  __shared__ float bsum[32];
  __shared__ float b2s[16];
  int tid = threadIdx.x;
  if (tid < 128){ w2[tid] = W2[tid]; wih[tid] = ((const float4*)Wih)[tid]; }
  if (tid < 32) bsum[tid] = bih[tid] + bhh[tid];
  if (tid < 16) b2s[tid] = b2[tid];
  __syncthreads();
  if (tid >= 250) return;
  int nl = tid/10;
  int t  = tid - nl*10;
  int n = blockIdx.x*25 + nl;
  float a0=0,a1=0,a2=0,a3=0,a4=0,a5=0,a6=0,a7=0;
  int e0 = row_start[n], e1 = row_start[n+1];
  int e = e0;
  for (; e + 4 <= e1; e += 4){
    int s0 = csr[e], s1 = csr[e+1], s2 = csr[e+2], s3 = csr[e+3];
    uint4 v0 = x2p[(long long)s0*10 + t];
    uint4 v1 = x2p[(long long)s1*10 + t];
    uint4 v2 = x2p[(long long)s2*10 + t];
    uint4 v3 = x2p[(long long)s3*10 + t];
    ACC8(v0) ACC8(v1) ACC8(v2) ACC8(v3)
  }
  for (; e < e1; ++e){
    int s = csr[e];
    uint4 v = x2p[(long long)s*10 + t];
    ACC8(v)
  }
  float sc = nd[n];
  float y[16];
  #pragma unroll
  for (int j = 0; j < 16; ++j){
    float s = a0*w2[0*16+j] + a1*w2[1*16+j] + a2*w2[2*16+j] + a3*w2[3*16+j]
            + a4*w2[4*16+j] + a5*w2[5*16+j] + a6*w2[6*16+j] + a7*w2[7*16+j];
    y[j] = fmaxf(s*sc + b2s[j], 0.f);
  }
  // gates g[0..31] = bsum[g] + y . Wih[g][:]  -> packed bf16, 4 x uint4 per (n,t)
  uint4* outp = xg + ((long long)n*10 + t)*4;
  #pragma unroll
  for (int g8 = 0; g8 < 4; ++g8){
    float gv[8];
    #pragma unroll
    for (int c = 0; c < 8; ++c){
      int g = g8*8 + c;
      float s = bsum[g];
      #pragma unroll
      for (int q = 0; q < 4; ++q){
        float4 wv = wih[g*4 + q];
        s += y[q*4+0]*wv.x + y[q*4+1]*wv.y + y[q*4+2]*wv.z + y[q*4+3]*wv.w;
      }
      gv[c] = s;
    }
    uint4 pk;
    pk.x = pack2(gv[0],gv[1]); pk.y = pack2(gv[2],gv[3]);
    pk.z = pack2(gv[4],gv[5]); pk.w = pack2(gv[6],gv[7]);
    outp[g8] = pk;
  }
}

// ---------------- LSTM over T=10 + max-pool reduce + fused head (last block) ----------------
__global__ __launch_bounds__(256) void k_lstm(const uint4* __restrict__ xg,
                                              const float* __restrict__ Whh,
                                              unsigned* __restrict__ maxbuf,
                                              int* __restrict__ done,
                                              const float* __restrict__ Wo,
                                              const float* __restrict__ bo,
                                              float* __restrict__ out,
                                              int nblocks){
  __shared__ float4 whh[64];   // (32,8) row-major as float4: whh[g*2+q]
  __shared__ unsigned smax[8];
  __shared__ int lastflag;
  int tid = threadIdx.x;
  if (tid < 64) whh[tid] = ((const float4*)Whh)[tid];
  if (tid < 8) smax[tid] = 0u;
  __syncthreads();
  int n = blockIdx.x*256 + tid;
  if (n < NN){
    float h[8] = {0,0,0,0,0,0,0,0};
    float c[8] = {0,0,0,0,0,0,0,0};
    const uint4* xr = xg + (long long)n*40; // [t][4 uint4] contiguous per node
    for (int t = 0; t < TW; ++t){
      float g[32];
      #pragma unroll
      for (int q = 0; q < 4; ++q){
        uint4 v = xr[t*4 + q];
        g[q*8+0]=bflo(v.x); g[q*8+1]=bfhi(v.x);
        g[q*8+2]=bflo(v.y); g[q*8+3]=bfhi(v.y);
        g[q*8+4]=bflo(v.z); g[q*8+5]=bfhi(v.z);
        g[q*8+6]=bflo(v.w); g[q*8+7]=bfhi(v.w);
      }
      #pragma unroll
      for (int gi = 0; gi < 32; ++gi){
        float4 wa = whh[gi*2+0], wb = whh[gi*2+1];
        g[gi] += h[0]*wa.x + h[1]*wa.y + h[2]*wa.z + h[3]*wa.w
               + h[4]*wb.x + h[5]*wb.y + h[6]*wb.z + h[7]*wb.w;
      }
      #pragma unroll
      for (int j = 0; j < 8; ++j){
        float ig = sigf(g[j]);
        float fg = sigf(g[8+j]);
        float gg = tanhfast(g[16+j]);
        float og = sigf(g[24+j]);
        c[j] = fg*c[j] + ig*gg;
        h[j] = og*tanhfast(c[j]);
      }
    }
    #pragma unroll
    for (int j = 0; j < 8; ++j){
      unsigned b = __float_as_uint(h[j]);
      unsigned u = (b & 0x80000000u) ? ~b : (b | 0x80000000u); // monotonic map
      atomicMax(&smax[j], u);
    }
  }
  __syncthreads();
  if (tid < 8) atomicMax(&maxbuf[tid], smax[tid]);
  __syncthreads();
  if (tid == 0){
    __threadfence();
    int prev = atomicAdd(done, 1);
    lastflag = (prev == nblocks - 1);
  }
  __syncthreads();
  if (lastflag && tid == 0){
    float m[8];
    #pragma unroll
    for (int j = 0; j < 8; ++j){
      unsigned u = atomicAdd(&maxbuf[j], 0u); // device-coherent read
      unsigned b = (u & 0x80000000u) ? (u ^ 0x80000000u) : ~u;
      m[j] = __uint_as_float(b);
    }
    #pragma unroll
    for (int o = 0; o < 4; ++o){
      float s = bo[o];
      #pragma unroll
      for (int k = 0; k < 8; ++k) s += m[k]*Wo[k*4 + o];
      out[o] = 1.0f/(1.0f + __expf(-s));
    }
  }
}

extern "C" void kernel_launch(void* const* d_in, const int* in_sizes, int n_in,
                              void* d_out, int out_size, void* d_ws, size_t ws_size,
                              hipStream_t stream) {
  const float* feat = (const float*)d_in[0];
  const int*   src  = (const int*)d_in[1];
  const int*   dst  = (const int*)d_in[2];
  const float* W1   = (const float*)d_in[3];
  const float* b1   = (const float*)d_in[4];
  const float* W2   = (const float*)d_in[5];
  const float* b2   = (const float*)d_in[6];
  const float* Wih  = (const float*)d_in[7];
  const float* Whh  = (const float*)d_in[8];
  const float* bih  = (const float*)d_in[9];
  const float* bhh  = (const float*)d_in[10];
  const float* Wo   = (const float*)d_in[11];
  const float* bo   = (const float*)d_in[12];
  float* out = (float*)d_out;

  // workspace layout
  const size_t SN = 50048; // padded node stride
  int*      dego      = (int*)d_ws;
  int*      degi      = dego + SN;
  int*      cursor    = degi + SN;   // cursor[NN..SN) unused -> zeroed scratch
  int*      done      = cursor + 50040; // inside zeroed region
  float*    ns        = (float*)(cursor + SN);
  float*    nd        = ns + SN;
  int*      row_start = (int*)(nd + SN);       // 50001 used, 50304 reserved
  int*      bsum      = row_start + 50304;     // 128
  unsigned* maxbuf    = (unsigned*)(bsum + 128); // 8 used, 64 reserved
  int*      csr       = (int*)(maxbuf + 64);   // 800000
  uint4*    h1        = (uint4*)(csr + 800000);   // 8 MB  [n][t]
  uint4*    x2p       = h1 + 500000;              // 8 MB  [n][t]
  uint4*    xg        = x2p + 500000;             // 32 MB [n][t][4]

  const int B = 256;
  k_zero  <<<(ZERO_U4 + B - 1)/B, B, 0, stream>>>((uint4*)d_ws);
  k_degree<<<(NE + B - 1)/B, B, 0, stream>>>(src, dst, dego, degi);

  const int NB = (NN + 511)/512; // 98
  k_scan1n<<<NB, 512, 0, stream>>>(degi, dego, bsum, ns, nd, maxbuf);
  k_scan3<<<NB, 512, 0, stream>>>(degi, bsum, row_start);
  k_fill <<<(NE + B - 1)/B, B, 0, stream>>>(src, dst, row_start, cursor, csr);

  k_conv1<<<CONV1_BLOCKS, B, 0, stream>>>(feat, W1, ns, h1);
  const int NBLK = NN/25; // 2000 blocks
  k_agg1 <<<NBLK, B, 0, stream>>>(h1, row_start, csr, ns, nd, b1, x2p);
  k_agg2 <<<NBLK, B, 0, stream>>>(x2p, row_start, csr, nd, W2, b2, Wih, bih, bhh, xg);
  const int LB = (NN + B - 1)/B; // 196
  k_lstm <<<LB, B, 0, stream>>>(xg, Whh, maxbuf, done, Wo, bo, out, LB);
}